// Round 3
// baseline (704.291 us; speedup 1.0000x reference)
//
#include <hip/hip_runtime.h>
#include <hip/hip_bf16.h>
#include <cstdint>
#include <cstddef>

#define TOKENS 4096
#define HIDDEN 2048
#define INTER  1408
#define NE     8
#define NGU    2816            // 2*INTER (gate | up, 16-col interleaved)
#define CAP_ROWS 9216          // >= 8192 assignments + 8*127 tile pad
#define LDSA   (128 * 32)      // one 128x32 bf16 slab

typedef __bf16 bf16;
typedef __bf16 bf16x8 __attribute__((ext_vector_type(8)));
typedef float  f32x4  __attribute__((ext_vector_type(4)));

__device__ __forceinline__ void async16(const void* g, void* l) {
  __builtin_amdgcn_global_load_lds((const __attribute__((address_space(1))) void*)g,
                                   (__attribute__((address_space(3))) void*)l,
                                   16, 0, 0);
}

// ---------------- router: logits, top-2, renorm weights, inverse index; x -> bf16 ----------------
__global__ void k_router(const float* __restrict__ x, const float* __restrict__ rw,
                         bf16* __restrict__ xb, int* __restrict__ cnt,
                         int* __restrict__ tok, float* __restrict__ wts,
                         int* __restrict__ inv) {
  const int w = threadIdx.x >> 6, l = threadIdx.x & 63;
  const int t = blockIdx.x * 4 + w;
  const float4* x4 = (const float4*)(x + (size_t)t * HIDDEN);
  const float4* r4 = (const float4*)rw;
  float acc[NE];
#pragma unroll
  for (int e = 0; e < NE; ++e) acc[e] = 0.f;
#pragma unroll
  for (int c = 0; c < 8; ++c) {
    const int idx = c * 64 + l;
    const float4 v = x4[idx];
    bf16* dst = xb + (size_t)t * HIDDEN + idx * 4;
    dst[0] = (bf16)v.x; dst[1] = (bf16)v.y; dst[2] = (bf16)v.z; dst[3] = (bf16)v.w;
#pragma unroll
    for (int e = 0; e < NE; ++e) {
      const float4 u = r4[e * 512 + idx];
      acc[e] += v.x * u.x + v.y * u.y + v.z * u.z + v.w * u.w;
    }
  }
#pragma unroll
  for (int e = 0; e < NE; ++e)
#pragma unroll
    for (int s = 32; s > 0; s >>= 1) acc[e] += __shfl_xor(acc[e], s, 64);
  if (l == 0) {
    int i0 = 0; float l0 = acc[0];
#pragma unroll
    for (int e = 1; e < NE; ++e) if (acc[e] > l0) { l0 = acc[e]; i0 = e; }
    int i1 = -1; float l1 = -3.4e38f;
#pragma unroll
    for (int e = 0; e < NE; ++e) if (e != i0 && acc[e] > l1) { l1 = acc[e]; i1 = e; }
    const float w0 = 1.f / (1.f + __expf(l1 - l0));
    const float w1 = 1.f - w0;
    int p = atomicAdd(&cnt[i0], 1);
    tok[i0 * 4096 + p] = t; wts[i0 * 4096 + p] = w0; inv[2 * t] = (i0 << 12) | p;
    p = atomicAdd(&cnt[i1], 1);
    tok[i1 * 4096 + p] = t; wts[i1 * 4096 + p] = w1; inv[2 * t + 1] = (i1 << 12) | p;
  }
}

// ---------------- 128-aligned exclusive scan of expert counts ----------------
__global__ void k_scan(const int* __restrict__ cnt, int* __restrict__ offs) {
  if (threadIdx.x == 0 && blockIdx.x == 0) {
    int o = 0;
    for (int e = 0; e < NE; ++e) { offs[e] = o; o += ((cnt[e] + 127) >> 7) << 7; }
    offs[NE] = o;
  }
}

// ---------------- merged 64x64 tiled transpose + fp32->bf16 for all 3 weights ----------------
// z in [0,8): gate (mode1), [8,16): up (mode2), [16,24): down (mode0)
__global__ __launch_bounds__(256) void k_tr(
    const float* __restrict__ wg, const float* __restrict__ wu,
    const float* __restrict__ wd, bf16* __restrict__ wgu, bf16* __restrict__ wdt) {
  const int z = blockIdx.z;
  int mode, R, C;
  const float* in; bf16* out;
  if (z < 16) {
    mode = (z < 8) ? 1 : 2;
    const int e = z & 7;
    in = (z < 8 ? wg : wu) + (size_t)e * HIDDEN * INTER;
    out = wgu + (size_t)e * NGU * HIDDEN;
    R = HIDDEN; C = INTER;
  } else {
    mode = 0;
    const int e = z - 16;
    in = wd + (size_t)e * INTER * HIDDEN;
    out = wdt + (size_t)e * HIDDEN * INTER;
    R = INTER; C = HIDDEN;
  }
  const int c0 = blockIdx.x * 64, r0 = blockIdx.y * 64;
  if (c0 >= C || r0 >= R) return;

  __shared__ float tile[64][68];
  const int t = threadIdx.x;
  const int row = t >> 4, cq = t & 15;
  const float* src = in + (size_t)(r0 + row) * C + c0 + cq * 4;
#pragma unroll
  for (int p = 0; p < 4; ++p) {
    const float4 v = *(const float4*)(src + (size_t)(p * 16) * C);
    *(float4*)&tile[p * 16 + row][cq * 4] = v;
  }
  __syncthreads();
  const int oc = t >> 2, rq = t & 3;
  float vals[16];
#pragma unroll
  for (int i = 0; i < 16; ++i) vals[i] = tile[rq * 16 + i][oc];
  const int c = c0 + oc;
  int p;
  if (mode == 0) p = c;
  else p = ((c >> 4) << 5) + (c & 15) + (mode == 2 ? 16 : 0);
  bf16x8 o0, o1;
#pragma unroll
  for (int i = 0; i < 8; ++i) { o0[i] = (bf16)vals[i]; o1[i] = (bf16)vals[8 + i]; }
  bf16* dst = out + (size_t)p * R + r0 + rq * 16;
  *(bf16x8*)dst = o0;
  *(bf16x8*)(dst + 8) = o1;
}

// ---------------- GEMM1: gathered X x interleaved [Wg|Wu]^T, fused silu*up*wts -> H ----------------
// BK=64 as two BK=32 slabs under a single barrier pair.
__global__ __launch_bounds__(256, 4) void k_gu(
    const bf16* __restrict__ X, const bf16* __restrict__ W, bf16* __restrict__ H,
    const int* __restrict__ cnt, const int* __restrict__ offs,
    const int* __restrict__ tok, const float* __restrict__ wts) {
  const int e = blockIdx.z, mt = blockIdx.y, nt = blockIdx.x;
  const int c = cnt[e];
  if (mt * 128 >= c) return;

  __shared__ bf16 sA[2 * LDSA];
  __shared__ bf16 sB[2 * LDSA];

  const int t = threadIdx.x, l = t & 63, w = t >> 6;
  const int iA0 = t, iA1 = t + 256;
  const int rA0 = iA0 >> 2, g0 = iA0 & 3;
  const int rA1 = iA1 >> 2, g1 = iA1 & 3;
  const int gr0 = tok[e * 4096 + (mt * 128 + rA0 < c ? mt * 128 + rA0 : c - 1)];
  const int gr1 = tok[e * 4096 + (mt * 128 + rA1 < c ? mt * 128 + rA1 : c - 1)];
  const bf16* pa0 = X + (size_t)gr0 * HIDDEN + g0 * 8;
  const bf16* pa1 = X + (size_t)gr1 * HIDDEN + g1 * 8;
  const bf16* pb0 = W + ((size_t)e * NGU + nt * 128 + rA0) * HIDDEN + g0 * 8;
  const bf16* pb1 = W + ((size_t)e * NGU + nt * 128 + rA1) * HIDDEN + g1 * 8;
  bf16* la0 = sA + iA0 * 8; bf16* la1 = sA + iA1 * 8;
  bf16* lb0 = sB + iA0 * 8; bf16* lb1 = sB + iA1 * 8;

  const int wm = (w >> 1) * 64, wn = (w & 1) * 64;
  const int r16 = l & 15, quad = l >> 4;
  const bf16* fA = sA + (wm + r16) * 32 + quad * 8;
  const bf16* fB = sB + (wn + r16) * 32 + quad * 8;

  f32x4 acc[4][4];
#pragma unroll
  for (int i = 0; i < 4; ++i)
#pragma unroll
    for (int j = 0; j < 4; ++j) acc[i][j] = (f32x4){0.f, 0.f, 0.f, 0.f};

  for (int kk = 0; kk < HIDDEN; kk += 64) {
    async16(pa0 + kk, la0);      async16(pa1 + kk, la1);
    async16(pb0 + kk, lb0);      async16(pb1 + kk, lb1);
    async16(pa0 + kk + 32, la0 + LDSA); async16(pa1 + kk + 32, la1 + LDSA);
    async16(pb0 + kk + 32, lb0 + LDSA); async16(pb1 + kk + 32, lb1 + LDSA);
    __syncthreads();
#pragma unroll
    for (int s = 0; s < 2; ++s) {
      const bf16* fAs = fA + s * LDSA;
      const bf16* fBs = fB + s * LDSA;
      bf16x8 a[4], b[4];
#pragma unroll
      for (int i = 0; i < 4; ++i) a[i] = *(const bf16x8*)(fAs + i * 16 * 32);
#pragma unroll
      for (int j = 0; j < 4; ++j) b[j] = *(const bf16x8*)(fBs + j * 16 * 32);
#pragma unroll
      for (int i = 0; i < 4; ++i)
#pragma unroll
        for (int j = 0; j < 4; ++j)
          acc[i][j] = __builtin_amdgcn_mfma_f32_16x16x32_bf16(a[i], b[j], acc[i][j], 0, 0, 0);
    }
    __syncthreads();
  }

  const int mLoc = mt * 128 + wm + quad * 4;
  const int hcol = nt * 64 + (wn >> 1) + r16;
#pragma unroll
  for (int i = 0; i < 4; ++i)
#pragma unroll
    for (int r = 0; r < 4; ++r) {
      const int m = mLoc + i * 16 + r;
      const int mc = m < c ? m : c - 1;
      const float ws = wts[e * 4096 + mc];
      const float g0v = acc[i][0][r], u0v = acc[i][1][r];
      const float g1v = acc[i][2][r], u1v = acc[i][3][r];
      const float h0 = (g0v / (1.f + __expf(-g0v))) * u0v * ws;
      const float h1 = (g1v / (1.f + __expf(-g1v))) * u1v * ws;
      bf16* dst = H + (size_t)(offs[e] + m) * INTER + hcol;
      dst[0]  = (bf16)h0;
      dst[16] = (bf16)h1;
    }
}

// ---------------- GEMM2: H x Wdown^T -> expert-major O2 (bf16, no atomics) ----------------
__global__ __launch_bounds__(256, 4) void k_dn(
    const bf16* __restrict__ Hin, const bf16* __restrict__ W, bf16* __restrict__ O2,
    const int* __restrict__ cnt, const int* __restrict__ offs) {
  const int e = blockIdx.z, mt = blockIdx.y, nt = blockIdx.x;
  const int c = cnt[e];
  if (mt * 128 >= c) return;

  __shared__ bf16 sA[2 * LDSA];
  __shared__ bf16 sB[2 * LDSA];

  const int t = threadIdx.x, l = t & 63, w = t >> 6;
  const int iA0 = t, iA1 = t + 256;
  const int rA0 = iA0 >> 2, g0 = iA0 & 3;
  const int rA1 = iA1 >> 2, g1 = iA1 & 3;
  const int base = offs[e] + mt * 128;
  const bf16* pa0 = Hin + (size_t)(base + rA0) * INTER + g0 * 8;
  const bf16* pa1 = Hin + (size_t)(base + rA1) * INTER + g1 * 8;
  const bf16* pb0 = W + ((size_t)e * HIDDEN + nt * 128 + rA0) * INTER + g0 * 8;
  const bf16* pb1 = W + ((size_t)e * HIDDEN + nt * 128 + rA1) * INTER + g1 * 8;
  bf16* la0 = sA + iA0 * 8; bf16* la1 = sA + iA1 * 8;
  bf16* lb0 = sB + iA0 * 8; bf16* lb1 = sB + iA1 * 8;

  const int wm = (w >> 1) * 64, wn = (w & 1) * 64;
  const int r16 = l & 15, quad = l >> 4;
  const bf16* fA = sA + (wm + r16) * 32 + quad * 8;
  const bf16* fB = sB + (wn + r16) * 32 + quad * 8;

  f32x4 acc[4][4];
#pragma unroll
  for (int i = 0; i < 4; ++i)
#pragma unroll
    for (int j = 0; j < 4; ++j) acc[i][j] = (f32x4){0.f, 0.f, 0.f, 0.f};

  for (int kk = 0; kk < INTER; kk += 64) {
    async16(pa0 + kk, la0);      async16(pa1 + kk, la1);
    async16(pb0 + kk, lb0);      async16(pb1 + kk, lb1);
    async16(pa0 + kk + 32, la0 + LDSA); async16(pa1 + kk + 32, la1 + LDSA);
    async16(pb0 + kk + 32, lb0 + LDSA); async16(pb1 + kk + 32, lb1 + LDSA);
    __syncthreads();
#pragma unroll
    for (int s = 0; s < 2; ++s) {
      const bf16* fAs = fA + s * LDSA;
      const bf16* fBs = fB + s * LDSA;
      bf16x8 a[4], b[4];
#pragma unroll
      for (int i = 0; i < 4; ++i) a[i] = *(const bf16x8*)(fAs + i * 16 * 32);
#pragma unroll
      for (int j = 0; j < 4; ++j) b[j] = *(const bf16x8*)(fBs + j * 16 * 32);
#pragma unroll
      for (int i = 0; i < 4; ++i)
#pragma unroll
        for (int j = 0; j < 4; ++j)
          acc[i][j] = __builtin_amdgcn_mfma_f32_16x16x32_bf16(a[i], b[j], acc[i][j], 0, 0, 0);
    }
    __syncthreads();
  }

  const int rowBase = offs[e] + mt * 128 + wm + quad * 4;
  const int colBase = nt * 128 + wn + r16;
#pragma unroll
  for (int i = 0; i < 4; ++i)
#pragma unroll
    for (int r = 0; r < 4; ++r) {
      bf16* dst = O2 + (size_t)(rowBase + i * 16 + r) * HIDDEN + colBase;
#pragma unroll
      for (int j = 0; j < 4; ++j) dst[j * 16] = (bf16)acc[i][j][r];
    }
}

// ---------------- combine: out[t] = O2[slot0(t)] + O2[slot1(t)] ----------------
__global__ void k_cb(const bf16* __restrict__ O2, const int* __restrict__ inv,
                     const int* __restrict__ offs, float* __restrict__ out) {
  const int t = blockIdx.x;
  const int col = threadIdx.x * 8;
  const int s0 = inv[2 * t], s1 = inv[2 * t + 1];
  const int r0 = offs[s0 >> 12] + (s0 & 4095);
  const int r1 = offs[s1 >> 12] + (s1 & 4095);
  const bf16x8 a = *(const bf16x8*)(O2 + (size_t)r0 * HIDDEN + col);
  const bf16x8 b = *(const bf16x8*)(O2 + (size_t)r1 * HIDDEN + col);
  float4 o0, o1;
  o0.x = (float)a[0] + (float)b[0]; o0.y = (float)a[1] + (float)b[1];
  o0.z = (float)a[2] + (float)b[2]; o0.w = (float)a[3] + (float)b[3];
  o1.x = (float)a[4] + (float)b[4]; o1.y = (float)a[5] + (float)b[5];
  o1.z = (float)a[6] + (float)b[6]; o1.w = (float)a[7] + (float)b[7];
  float* dst = out + (size_t)t * HIDDEN + col;
  *(float4*)dst = o0;
  *(float4*)(dst + 4) = o1;
}

extern "C" void kernel_launch(void* const* d_in, const int* in_sizes, int n_in,
                              void* d_out, int out_size, void* d_ws, size_t ws_size,
                              hipStream_t stream) {
  const float* x  = (const float*)d_in[0];
  const float* rw = (const float*)d_in[1];
  const float* wg = (const float*)d_in[2];
  const float* wu = (const float*)d_in[3];
  const float* wd = (const float*)d_in[4];
  float* out = (float*)d_out;

  char* ws = (char*)d_ws;
  size_t o = 0;
  auto alloc = [&](size_t b) { void* p = ws + o; o += (b + 255) & ~(size_t)255; return p; };
  int*   cnt  = (int*)alloc(NE * 4);
  int*   offs = (int*)alloc((NE + 1) * 4);
  int*   tok  = (int*)alloc((size_t)NE * 4096 * 4);
  float* wts  = (float*)alloc((size_t)NE * 4096 * 4);
  int*   inv  = (int*)alloc((size_t)TOKENS * 2 * 4);
  bf16*  xb   = (bf16*)alloc((size_t)TOKENS * HIDDEN * 2);
  bf16*  wgu  = (bf16*)alloc((size_t)NE * NGU * HIDDEN * 2);
  bf16*  wdt  = (bf16*)alloc((size_t)NE * HIDDEN * INTER * 2);
  bf16*  h    = (bf16*)alloc((size_t)CAP_ROWS * INTER * 2);
  bf16*  o2   = (bf16*)alloc((size_t)CAP_ROWS * HIDDEN * 2);

  hipMemsetAsync(cnt, 0, NE * 4, stream);

  k_router<<<TOKENS / 4, 256, 0, stream>>>(x, rw, xb, cnt, tok, wts, inv);
  k_scan<<<1, 64, 0, stream>>>(cnt, offs);
  k_tr<<<dim3(32, 32, 24), 256, 0, stream>>>(wg, wu, wd, wgu, wdt);
  k_gu<<<dim3(NGU / 128, TOKENS / 128, NE), 256, 0, stream>>>(xb, wgu, h, cnt, offs, tok, wts);
  k_dn<<<dim3(HIDDEN / 128, TOKENS / 128, NE), 256, 0, stream>>>(h, wdt, o2, cnt, offs);
  k_cb<<<TOKENS, 256, 0, stream>>>(o2, inv, offs, out);
}